// Round 1
// baseline (590.592 us; speedup 1.0000x reference)
//
#include <hip/hip_runtime.h>
#include <math.h>

// LocalAggregationLoss:
//   v = normalize(codes)                        [1024,128]
//   d1[b] = sum_k exp(dot(bank[idx_bg[b,k]], v[b]) / T)
//   d2[b] = sum_k exp(dot(bank[idx_cl[b,k]], v[b]) / T)
//   out[b] = log(d1[b]) - log(d2[b])
//
// R2: MLP/duty-cycle fix. Effective gather BW was 0.36-0.7 TB/s vs 6.3
// achievable -> latency-bound, not BW-bound. Restructure as a
// global_load_lds gather pipeline:
//   - 4 waves/block, each wave owns one (list, half-of-K) quadrant (100 rows)
//   - tiles of 4 rows (2 KB) staged direct-to-LDS (2 gll/tile, 1KB each)
//   - triple-buffered, prefetch depth 2, counted s_waitcnt vmcnt(4)
//     (never 0 in the main loop) -> ~4KB sustained in flight per wave
//   - no __syncthreads in main loop (per-wave buffers, per-wave vmcnt)
//   - consume: 16 lanes/row, 2 ds_read_b128 + 8 FMA + 4 width-16 shuffles
//     (DPP) + 1 exp per 4 rows  (was 10 shuffles + 2 exp per 2 rows)
//   - VGPR pressure collapses (no reg-held row buffers) -> 6 blocks/CU
//     (LDS-limited: 26.7KB/block), 24 waves/CU vs 16 before.

constexpr int DIM   = 128;
constexpr int KN    = 200;
constexpr int HALF  = 100;            // rows per wave (one quadrant)
constexpr int TROWS = 4;              // rows per tile
constexpr int NT    = HALF / TROWS;   // 25 tiles per wave
constexpr float INV_T = 1.0f / 0.07f;

typedef const __attribute__((address_space(1))) void gvoid_t;
typedef __attribute__((address_space(3))) void lvoid_t;

__global__ __launch_bounds__(256, 6)
void lal_kernel(const float* __restrict__ codes,
                const float* __restrict__ bank,
                const int*   __restrict__ idx_bg,
                const int*   __restrict__ idx_cl,
                float*       __restrict__ out)
{
    const int b    = blockIdx.x;
    const int tid  = threadIdx.x;
    const int w    = tid >> 6;        // wave 0..3: list = w>>1, half = w&1
    const int lane = tid & 63;

    __shared__ alignas(16) float v[DIM];
    __shared__ int   s_idx[4 * HALF];                 // per-wave index slabs
    __shared__ alignas(16) float tiles[4][3][TROWS * DIM];  // 24 KB, 3 bufs/wave
    __shared__ float wsum[4];
    __shared__ float red[4];
    __shared__ float s_rnorm;

    // ---- each wave stages its own 100 indices into LDS ----
    // (main loop must contain NO global loads other than gll, so the
    //  counted vmcnt immediates stay exact)
    const int* ip    = (w < 2) ? idx_bg : idx_cl;
    const int  kbase = (w & 1) * HALF;
    for (int k = lane; k < HALF; k += 64)
        s_idx[w * HALF + k] = ip[b * KN + kbase + k];

    // ---- normalize codes[b] into LDS ----
    float c  = (tid < DIM) ? codes[b * DIM + tid] : 0.0f;
    float ss = c * c;
    #pragma unroll
    for (int m = 32; m > 0; m >>= 1) ss += __shfl_xor(ss, m, 64);
    if ((tid & 63) == 0) wsum[tid >> 6] = ss;
    __syncthreads();
    if (tid == 0) {
        float t = wsum[0] + wsum[1] + wsum[2] + wsum[3];
        s_rnorm = 1.0f / sqrtf(t);
    }
    __syncthreads();
    if (tid < DIM) v[tid] = c * s_rnorm;
    __syncthreads();                 // also drains all prologue vmem (vmcnt=0)

    // ---- per-lane fixed fragments ----
    const int s = lane & 15;         // 16 lanes per row, lane's float4 slot
    const int r = lane >> 4;         // which tile-row this lane reduces
    const float4 vv0 = ((const float4*)v)[s];
    const float4 vv1 = ((const float4*)v)[s + 16];

    const float* bank_lane = bank + (lane & 31) * 4;  // this lane's 16B chunk
    const int*   midx = &s_idx[w * HALF];
    float* const tb   = &tiles[w][0][0];
    float sum = 0.0f;

    // stage tile t (4 rows) into buffer bsel: 2x global_load_lds, 1KB each.
    // gll LDS dst = wave-uniform base + lane*16 -> rows land contiguous:
    //   lanes 0-31 -> row 4t+2i, lanes 32-63 -> row 4t+2i+1.
    auto STAGE = [&](int t, int bsel) {
        int r0 = midx[4 * t     + (lane >> 5)];
        int r1 = midx[4 * t + 2 + (lane >> 5)];
        const float* g0 = bank_lane + (size_t)r0 * DIM;
        const float* g1 = bank_lane + (size_t)r1 * DIM;
        float* d0 = tb + bsel * (TROWS * DIM);
        float* d1 = d0 + 2 * DIM;
        __builtin_amdgcn_global_load_lds((gvoid_t*)g0, (lvoid_t*)d0, 16, 0, 0);
        __builtin_amdgcn_global_load_lds((gvoid_t*)g1, (lvoid_t*)d1, 16, 0, 0);
    };

    // consume tile in buffer bsel: lane group r (16 lanes) reduces row r.
    auto COMPUTE = [&](int bsel) {
        const float4* T = (const float4*)(tb + bsel * (TROWS * DIM));
        float4 x0 = T[r * 32 + s];        // row r, chunk s
        float4 x1 = T[r * 32 + s + 16];   // row r, chunk s+16
        float d = x0.x * vv0.x + x0.y * vv0.y + x0.z * vv0.z + x0.w * vv0.w
                + x1.x * vv1.x + x1.y * vv1.y + x1.z * vv1.z + x1.w * vv1.w;
        d += __shfl_xor(d, 1, 16);
        d += __shfl_xor(d, 2, 16);
        d += __shfl_xor(d, 4, 16);
        d += __shfl_xor(d, 8, 16);
        float e = __expf(d * INV_T);
        if (s == 0) sum += e;             // one add per row
    };

    // ---- software-pipelined gather: depth-2 prefetch, counted vmcnt ----
    STAGE(0, 0);
    STAGE(1, 1);
    int bsel = 0;
    for (int t = 0; t < NT - 2; ++t) {
        STAGE(t + 2, (bsel + 2) % 3);
        // wait until tile t's 2 glls landed; keep t+1,t+2 (4 loads) in flight
        asm volatile("s_waitcnt vmcnt(4)" ::: "memory");
        COMPUTE(bsel);
        // fence: next iteration's glls must not drift above these ds_reads
        __builtin_amdgcn_sched_barrier(0);
        bsel = (bsel + 1) % 3;
    }
    asm volatile("s_waitcnt vmcnt(2)" ::: "memory");
    COMPUTE(bsel);                        // tile NT-2
    bsel = (bsel + 1) % 3;
    asm volatile("s_waitcnt vmcnt(0)" ::: "memory");
    COMPUTE(bsel);                        // tile NT-1

    // ---- combine: wave partial -> block result ----
    #pragma unroll
    for (int m = 32; m > 0; m >>= 1) sum += __shfl_xor(sum, m, 64);
    if (lane == 0) red[w] = sum;
    __syncthreads();
    if (tid == 0)
        out[b] = logf(red[0] + red[1]) - logf(red[2] + red[3]);
}

extern "C" void kernel_launch(void* const* d_in, const int* in_sizes, int n_in,
                              void* d_out, int out_size, void* d_ws, size_t ws_size,
                              hipStream_t stream)
{
    const float* codes  = (const float*)d_in[0];
    const float* bank   = (const float*)d_in[1];
    const int*   idx_bg = (const int*)d_in[2];
    const int*   idx_cl = (const int*)d_in[3];
    float*       out    = (float*)d_out;

    const int batch = in_sizes[0] / DIM;   // 1024
    lal_kernel<<<batch, 256, 0, stream>>>(codes, bank, idx_bg, idx_cl, out);
}